// Round 16
// baseline (850.890 us; speedup 1.0000x reference)
//
#include <hip/hip_runtime.h>

#define DIM 2048
#define HDIM 128
#define NH 16
#define SEQ 2048
#define BATCH 2
#define MROWS (BATCH*SEQ)   // 4096
#define QKP 6144            // qkv row pitch (q|k|v concatenated)

typedef __attribute__((ext_vector_type(8))) short short8;
typedef __attribute__((ext_vector_type(4))) float f32x4;

template<int N> struct ic { static constexpr int value = N; };

__device__ __forceinline__ unsigned short f2bf(float f) {
  union { float f; unsigned u; } v; v.f = f;
  unsigned r = v.u + 0x7FFFu + ((v.u >> 16) & 1u);
  return (unsigned short)(r >> 16);
}
__device__ __forceinline__ float bf2f(unsigned short b) {
  union { unsigned u; float f; } v; v.u = ((unsigned)b) << 16;
  return v.f;
}

__device__ __forceinline__ void gload16(const void* g, void* l) {
  __builtin_amdgcn_global_load_lds((const __attribute__((address_space(1))) unsigned int*)g,
                                   (__attribute__((address_space(3))) unsigned int*)l,
                                   16, 0, 0);
}

// ---------------- RMSNorm: fp32 [rows][2048] -> bf16 ----------------
__global__ __launch_bounds__(256) void rmsnorm_kernel(const float* __restrict__ x,
                                                      const float* __restrict__ w,
                                                      unsigned short* __restrict__ out) {
  const int row = blockIdx.x;
  const int t = threadIdx.x;
  const float* xr = x + (size_t)row * DIM;
  float4 v0 = ((const float4*)xr)[t*2];
  float4 v1 = ((const float4*)xr)[t*2+1];
  float ss = v0.x*v0.x + v0.y*v0.y + v0.z*v0.z + v0.w*v0.w
           + v1.x*v1.x + v1.y*v1.y + v1.z*v1.z + v1.w*v1.w;
  #pragma unroll
  for (int i = 1; i < 64; i <<= 1) ss += __shfl_xor(ss, i);
  __shared__ float red[4];
  if ((t & 63) == 0) red[t >> 6] = ss;
  __syncthreads();
  float sum = red[0] + red[1] + red[2] + red[3];
  float sc = rsqrtf(sum * (1.0f/DIM) + 1e-6f);
  const float* wr = w + t*8;
  unsigned short ob[8];
  ob[0] = f2bf(v0.x*sc*wr[0]); ob[1] = f2bf(v0.y*sc*wr[1]);
  ob[2] = f2bf(v0.z*sc*wr[2]); ob[3] = f2bf(v0.w*sc*wr[3]);
  ob[4] = f2bf(v1.x*sc*wr[4]); ob[5] = f2bf(v1.y*sc*wr[5]);
  ob[6] = f2bf(v1.z*sc*wr[6]); ob[7] = f2bf(v1.w*sc*wr[7]);
  uint4 pk;
  pk.x = (unsigned)ob[0] | ((unsigned)ob[1] << 16);
  pk.y = (unsigned)ob[2] | ((unsigned)ob[3] << 16);
  pk.z = (unsigned)ob[4] | ((unsigned)ob[5] << 16);
  pk.w = (unsigned)ob[6] | ((unsigned)ob[7] << 16);
  *((uint4*)(out + (size_t)row*DIM + t*8)) = pk;
}

// ------- Wide transpose+cast: fp32 [K][N] -> bf16 [N][K], 64x64 tiles, z selects src -------
__global__ __launch_bounds__(256) void transpose3_kernel(const float* __restrict__ W0,
                                                         const float* __restrict__ W1,
                                                         const float* __restrict__ W2,
                                                         unsigned short* __restrict__ D0,
                                                         unsigned short* __restrict__ D1,
                                                         unsigned short* __restrict__ D2,
                                                         int K, int N) {
  const float* W = blockIdx.z == 0 ? W0 : (blockIdx.z == 1 ? W1 : W2);
  unsigned short* D = blockIdx.z == 0 ? D0 : (blockIdx.z == 1 ? D1 : D2);
  __shared__ float tile[64][65];
  const int k0 = blockIdx.x*64, n0 = blockIdx.y*64;
  const int t = threadIdx.x;
  const int rr = t >> 4, cc = (t & 15) * 4;
  #pragma unroll
  for (int i=0;i<4;i++) {
    float4 v = *(const float4*)&W[(size_t)(k0 + rr + i*16)*N + n0 + cc];
    tile[rr+i*16][cc] = v.x; tile[rr+i*16][cc+1] = v.y;
    tile[rr+i*16][cc+2] = v.z; tile[rr+i*16][cc+3] = v.w;
  }
  __syncthreads();
  #pragma unroll
  for (int j=0;j<4;j++) {
    const int n = rr + j*16;
    uint2 pk;
    pk.x = (unsigned)f2bf(tile[cc  ][n]) | ((unsigned)f2bf(tile[cc+1][n]) << 16);
    pk.y = (unsigned)f2bf(tile[cc+2][n]) | ((unsigned)f2bf(tile[cc+3][n]) << 16);
    *(uint2*)&D[(size_t)(n0 + n)*K + k0 + cc] = pk;
  }
}

// ------------- V transpose (bf16): [b*S][vpitch cols 0..2047] -> [b*2048][S] -------------
__global__ __launch_bounds__(256) void transpose_v_kernel(const unsigned short* __restrict__ v,
                                                          int vpitch,
                                                          unsigned short* __restrict__ vt) {
  __shared__ unsigned short tile[32][33];
  const int b = blockIdx.z;
  const int s0 = blockIdx.x*32, c0 = blockIdx.y*32;
  const int tx = threadIdx.x & 31, ty = threadIdx.x >> 5;
  #pragma unroll
  for (int i=0;i<4;i++) tile[ty+i*8][tx] = v[((size_t)(b*SEQ + s0+ty+i*8))*vpitch + c0+tx];
  __syncthreads();
  #pragma unroll
  for (int i=0;i<4;i++) vt[((size_t)(b*DIM + c0+ty+i*8))*SEQ + s0+tx] = tile[tx][ty+i*8];
}

// ------------- RoPE in-place on q|k halves of qkv buffer [4096][QKP] -------------
__global__ __launch_bounds__(256) void rope_qk(unsigned short* __restrict__ qk,
                                               const float* __restrict__ cosb,
                                               const float* __restrict__ sinb) {
  const size_t idx = (size_t)blockIdx.x * 256 + threadIdx.x; // pair index
  const int d = (int)(idx & 63);
  const int h = (int)((idx >> 6) & 31);   // 32 head-slots: q heads 0-15, k heads 16-31
  const int row = (int)(idx >> 11);       // 0..4095
  const int s = row & (SEQ-1);
  const size_t base = (size_t)row * QKP + h*HDIM + d;
  float a  = bf2f(qk[base]);
  float bq = bf2f(qk[base+64]);
  float c1 = cosb[s*HDIM + d],    s1 = sinb[s*HDIM + d];
  float c2 = cosb[s*HDIM + d+64], s2 = sinb[s*HDIM + d+64];
  qk[base]    = f2bf(a*c1 - bq*s1);
  qk[base+64] = f2bf(bq*c2 + a*s2);
}

// ------------- BK=32 8-phase pipelined GEMM, BM=256: 64KB LDS -> 2 blocks/CU -------------
// Same schedule topology as r10, half the per-phase volume. Stage = 1 gload16/thread
// per half-tile (128x32). Swizzle sw(r)=(r^(r>>2))&3 (2-bit; naive r&3 collides rows
// mod 4 -> r13's 1.7e7 conflicts). vmcnt(2) at P3/P7 (ledger: retires exactly the
// next-consumed tile's A+B; next B stays in flight). 2 blocks/CU -> cross-block TLP
// hides barrier/drain waits (m114 mechanism).
template<int EPI>
__global__ __launch_bounds__(512, 2) void gemm_pipe32(const unsigned short* __restrict__ A,
                                                      const unsigned short* __restrict__ Bt,
                                                      const float* __restrict__ aux,
                                                      void* __restrict__ outp,
                                                      int M, int N, int K) {
  extern __shared__ unsigned short ldsd[];   // A: 4x4096 shorts, B: 4x4096 -> 64KB
  const int tid = threadIdx.x, l = tid & 63, wid = tid >> 6;
  const int wm = wid >> 2, wn = wid & 3;
  const int lr = l & 15, lg = l >> 4;
  const int bh = wn >> 1, brow0 = (wn & 1)*64;

  const int nbx = N >> 8;
  const int SW = (nbx >= 8) ? (nbx >> 3) : 1;
  const int xcd = (int)blockIdx.x & 7;
  const int ii  = (int)blockIdx.x >> 3;
  const int by = ii / SW;
  const int bx = xcd * SW + (ii % SW);
  const int m0 = by * 256, n0 = bx * 256;

  // read-side swizzle: thread-constant (mf-independent since 16 = 0 mod 4)
  const int jks = ((lg ^ ((lr ^ (lr >> 2)) & 3)) << 3);       // shorts
  const unsigned short* ldsA0 = ldsd + wm*4096 + lr*32 + jks;
  const unsigned short* ldsB0 = ldsd + 16384 + bh*4096 + brow0*32 + lr*32 + jks;

  // stage-side: thread t -> row t>>2, slot t&3; source col pre-swizzled
  const int srow = tid >> 2;
  const int jsw = (((tid & 3) ^ ((srow ^ (srow >> 2)) & 3)) << 3);
  const unsigned short* srcA[2];
  const unsigned short* srcB[2];
  #pragma unroll
  for (int h=0;h<2;h++) {
    srcA[h] = A  + (size_t)(m0 + h*128 + srow)*K + jsw;
    srcB[h] = Bt + (size_t)(n0 + h*128 + srow)*K + jsw;
  }
  unsigned short* dstL = ldsd + tid*8;

  int kO = 0;   // shorts: T*32
  auto stA = [&](int db, int half, int tiled) {
    gload16(srcA[half] + kO + tiled, dstL + (db*2+half)*4096);
  };
  auto stB = [&](int db, int half, int tiled) {
    gload16(srcB[half] + kO + tiled, dstL + 16384 + (db*2+half)*4096);
  };

  f32x4 acc[8][4] = {};
  short8 bfrag[4];
  const int ntile = K >> 5;

  // prologue: B(0) 2, A(0) 2, B(1) 2 in flight -> confirm B(0)+A(0)
  stB(0,0,0); stB(0,1,0);
  stA(0,0,0); stA(0,1,0);
  stB(1,0,32); stB(1,1,32);
  asm volatile("s_waitcnt vmcnt(2)" ::: "memory");
  __builtin_amdgcn_sched_barrier(0);
  __builtin_amdgcn_s_barrier();

  auto phase = [&](auto PC, auto LC) {
    constexpr int P = decltype(PC)::value;
    constexpr int LAST = decltype(LC)::value;
    constexpr int hi = P >> 2;    // 0: tile T (dbuf0), 1: tile T+1 (dbuf1)
    constexpr int p  = P & 3;
    if constexpr (p == 0) {
      const unsigned short* bB = ldsB0 + hi*2*4096;
      #pragma unroll
      for (int nf=0;nf<4;nf++) bfrag[nf] = *(const short8*)(bB + nf*512);
    }
    const unsigned short* aB = ldsA0 + hi*2*4096;
    short8 afr[2];
    afr[0] = *(const short8*)(aB + (p*2  )*512);
    afr[1] = *(const short8*)(aB + (p*2+1)*512);
    if constexpr (P == 0)      stA(1, 0, 32);
    else if constexpr (P == 1) stA(1, 1, 32);
    else if constexpr (!LAST) {
      if constexpr (P == 2)      stB(0, 0, 64);
      else if constexpr (P == 3) stB(0, 1, 64);
      else if constexpr (P == 4) stA(0, 0, 64);
      else if constexpr (P == 5) stA(0, 1, 64);
      else if constexpr (P == 6) stB(1, 0, 96);
      else if constexpr (P == 7) stB(1, 1, 96);
    }
    if constexpr (P == 3) {
      if constexpr (LAST) { asm volatile("s_waitcnt vmcnt(0)" ::: "memory"); }
      else                { asm volatile("s_waitcnt vmcnt(2)" ::: "memory"); }
    }
    if constexpr (P == 7 && !LAST) {
      asm volatile("s_waitcnt vmcnt(2)" ::: "memory");
    }
    __builtin_amdgcn_s_barrier();
    asm volatile("s_waitcnt lgkmcnt(0)" ::: "memory");
    __builtin_amdgcn_sched_barrier(0);
    __builtin_amdgcn_s_setprio(1);
    #pragma unroll
    for (int mi=0;mi<2;mi++)
      #pragma unroll
      for (int nf=0;nf<4;nf++)
        acc[p*2+mi][nf] = __builtin_amdgcn_mfma_f32_16x16x32_bf16(afr[mi], bfrag[nf], acc[p*2+mi][nf], 0,0,0);
    __builtin_amdgcn_s_setprio(0);
    __builtin_amdgcn_s_barrier();
  };

  for (int T = 0; T + 2 < ntile; T += 2, kO += 64) {
    phase(ic<0>{}, ic<0>{}); phase(ic<1>{}, ic<0>{});
    phase(ic<2>{}, ic<0>{}); phase(ic<3>{}, ic<0>{});
    phase(ic<4>{}, ic<0>{}); phase(ic<5>{}, ic<0>{});
    phase(ic<6>{}, ic<0>{}); phase(ic<7>{}, ic<0>{});
  }
  phase(ic<0>{}, ic<1>{}); phase(ic<1>{}, ic<1>{});
  phase(ic<2>{}, ic<1>{}); phase(ic<3>{}, ic<1>{});
  phase(ic<4>{}, ic<1>{}); phase(ic<5>{}, ic<1>{});
  phase(ic<6>{}, ic<1>{}); phase(ic<7>{}, ic<1>{});

  #pragma unroll
  for (int mf = 0; mf < 8; mf++)
    #pragma unroll
    for (int nf = 0; nf < 4; nf++)
      #pragma unroll
      for (int r = 0; r < 4; r++) {
        const int row = m0 + wm*128 + mf*16 + lg*4 + r;
        const int col = n0 + wn*64 + nf*16 + lr;
        const size_t idx = (size_t)row * N + col;
        if constexpr (EPI == 0) {
          ((unsigned short*)outp)[idx] = f2bf(acc[mf][nf][r]);
        } else if constexpr (EPI == 1) {
          ((float*)outp)[idx] = acc[mf][nf][r] + aux[idx];
        } else {
          float g = acc[mf][nf][r];
          float u = bf2f(((unsigned short*)outp)[idx]);
          float sg = u / (1.0f + __expf(-u));
          ((unsigned short*)outp)[idx] = f2bf(sg * g);
        }
      }
}

// ------------- 8-phase pipelined GEMM (r10) — kept for BM=128 (wo, w2) -------------
template<int BM, int EPI>
__global__ __launch_bounds__(512, 2) void gemm_pipe(const unsigned short* __restrict__ A,
                                                    const unsigned short* __restrict__ Bt,
                                                    const float* __restrict__ aux,
                                                    void* __restrict__ outp,
                                                    int M, int N, int K) {
  constexpr int HRA = BM/2;
  constexpr int MF  = BM/32;
  constexpr int APP = MF/4;
  constexpr int LA  = BM/128;
  constexpr int AHS = HRA*64;
  constexpr int BB  = 4*AHS;
  extern __shared__ unsigned short ldsd[];
  const int tid = threadIdx.x, l = tid & 63, wid = tid >> 6;
  const int wm = wid >> 2, wn = wid & 3;
  const int lr = l & 15, lg = l >> 4;
  const int bh = wn >> 1, brow0 = (wn & 1)*64;

  const int nbx = N >> 8;
  const int SW = (nbx >= 8) ? (nbx >> 3) : 1;
  const int xcd = (int)blockIdx.x & 7;
  const int ii  = (int)blockIdx.x >> 3;
  const int by = ii / SW;
  const int bx = xcd * SW + (ii % SW);
  const int m0 = by * BM, n0 = bx * 256;

  const int m7 = lr & 7;
  const int jks0 = ((lg    ) ^ m7) << 3;
  const int jks1 = ((4 + lg) ^ m7) << 3;
  const unsigned short* ldsA0 = ldsd + wm*AHS + lr*64;
  const unsigned short* ldsA1 = ldsA0 + 2*AHS;
  const unsigned short* ldsB0 = ldsd + BB + bh*8192 + (brow0+lr)*64;
  const unsigned short* ldsB1 = ldsB0 + 2*8192;

  const int r0 = tid >> 3;
  const int jsw = ((tid & 7) ^ (r0 & 7)) << 3;
  const unsigned short* srcA[2][LA];
  #pragma unroll
  for (int h=0;h<2;h++)
    #pragma unroll
    for (int c=0;c<LA;c++)
      srcA[h][c] = A + (size_t)(m0 + h*HRA + c*64 + r0)*K + jsw;
  const unsigned short* srcB[2][2];
  #pragma unroll
  for (int h=0;h<2;h++)
    #pragma unroll
    for (int c=0;c<2;c++)
      srcB[h][c] = Bt + (size_t)(n0 + h*128 + c*64 + r0)*K + jsw;
  unsigned short* dstL = ldsd + tid*8;

  int kO = 0;
  auto stA = [&](int db, int half, int tiled) {
    #pragma unroll
    for (int c=0;c<LA;c++)
      gload16(srcA[half][c] + kO + tiled, dstL + (db*2+half)*AHS + c*4096);
  };
  auto stB = [&](int db, int half, int tiled) {
    #pragma unroll
    for (int c=0;c<2;c++)
      gload16(srcB[half][c] + kO + tiled, dstL + BB + (db*2+half)*8192 + c*4096);
  };

  f32x4 acc[MF][4] = {};
  short8 bfrag[4][2];
  const int ntile = K >> 6;

  stB(0,0,0); stB(0,1,0);
  stA(0,0,0); stA(0,1,0);
  stB(1,0,64); stB(1,1,64);
  asm volatile("s_waitcnt vmcnt(4)" ::: "memory");
  __builtin_amdgcn_sched_barrier(0);
  __builtin_amdgcn_s_barrier();

  auto phase = [&](auto PC, auto LC) {
    constexpr int P = decltype(PC)::value;
    constexpr int LAST = decltype(LC)::value;
    constexpr int hi = P >> 2;
    constexpr int p  = P & 3;
    if constexpr (p == 0) {
      const unsigned short* bB = hi ? ldsB1 : ldsB0;
      #pragma unroll
      for (int nf=0;nf<4;nf++) {
        bfrag[nf][0] = *(const short8*)(bB + nf*1024 + jks0);
        bfrag[nf][1] = *(const short8*)(bB + nf*1024 + jks1);
      }
    }
    const unsigned short* aB = hi ? ldsA1 : ldsA0;
    short8 afr[APP][2];
    #pragma unroll
    for (int mi=0;mi<APP;mi++) {
      afr[mi][0] = *(const short8*)(aB + (p*APP+mi)*1024 + jks0);
      afr[mi][1] = *(const short8*)(aB + (p*APP+mi)*1024 + jks1);
    }
    if constexpr (P == 0)      stA(1, 0, 64);
    else if constexpr (P == 1) stA(1, 1, 64);
    else if constexpr (!LAST) {
      if constexpr (P == 2)      stB(0, 0, 128);
      else if constexpr (P == 3) stB(0, 1, 128);
      else if constexpr (P == 4) stA(0, 0, 128);
      else if constexpr (P == 5) stA(0, 1, 128);
      else if constexpr (P == 6) stB(1, 0, 192);
      else if constexpr (P == 7) stB(1, 1, 192);
    }
    if constexpr (p == 0) {
      asm volatile("s_waitcnt lgkmcnt(8)" ::: "memory");
    }
    if constexpr (P == 3) {
      if constexpr (LAST) { asm volatile("s_waitcnt vmcnt(0)" ::: "memory"); }
      else                { asm volatile("s_waitcnt vmcnt(4)" ::: "memory"); }
    }
    if constexpr (P == 7 && !LAST) {
      asm volatile("s_waitcnt vmcnt(4)" ::: "memory");
    }
    __builtin_amdgcn_s_barrier();
    asm volatile("s_waitcnt lgkmcnt(0)" ::: "memory");
    __builtin_amdgcn_sched_barrier(0);
    __builtin_amdgcn_s_setprio(1);
    #pragma unroll
    for (int mi=0;mi<APP;mi++)
      #pragma unroll
      for (int nf=0;nf<4;nf++)
        #pragma unroll
        for (int ks=0;ks<2;ks++)
          acc[p*APP+mi][nf] = __builtin_amdgcn_mfma_f32_16x16x32_bf16(afr[mi][ks], bfrag[nf][ks], acc[p*APP+mi][nf], 0,0,0);
    __builtin_amdgcn_s_setprio(0);
    __builtin_amdgcn_s_barrier();
  };

  for (int T = 0; T + 2 < ntile; T += 2, kO += 128) {
    phase(ic<0>{}, ic<0>{}); phase(ic<1>{}, ic<0>{});
    phase(ic<2>{}, ic<0>{}); phase(ic<3>{}, ic<0>{});
    phase(ic<4>{}, ic<0>{}); phase(ic<5>{}, ic<0>{});
    phase(ic<6>{}, ic<0>{}); phase(ic<7>{}, ic<0>{});
  }
  phase(ic<0>{}, ic<1>{}); phase(ic<1>{}, ic<1>{});
  phase(ic<2>{}, ic<1>{}); phase(ic<3>{}, ic<1>{});
  phase(ic<4>{}, ic<1>{}); phase(ic<5>{}, ic<1>{});
  phase(ic<6>{}, ic<1>{}); phase(ic<7>{}, ic<1>{});

  #pragma unroll
  for (int mf = 0; mf < MF; mf++)
    #pragma unroll
    for (int nf = 0; nf < 4; nf++)
      #pragma unroll
      for (int r = 0; r < 4; r++) {
        const int row = m0 + wm*HRA + mf*16 + lg*4 + r;
        const int col = n0 + wn*64 + nf*16 + lr;
        const size_t idx = (size_t)row * N + col;
        if constexpr (EPI == 0) {
          ((unsigned short*)outp)[idx] = f2bf(acc[mf][nf][r]);
        } else if constexpr (EPI == 1) {
          ((float*)outp)[idx] = acc[mf][nf][r] + aux[idx];
        } else {
          float g = acc[mf][nf][r];
          float u = bf2f(((unsigned short*)outp)[idx]);
          float sg = u / (1.0f + __expf(-u));
          ((unsigned short*)outp)[idx] = f2bf(sg * g);
        }
      }
}

// ------------- Flash attention (causal), 128-row q-tiles, KVBLK=64 -------------
__global__ __launch_bounds__(256, 2) void attn_kernel(const unsigned short* __restrict__ q,
                                                      const unsigned short* __restrict__ k,
                                                      const unsigned short* __restrict__ vt,
                                                      unsigned short* __restrict__ ao) {
  const int t = threadIdx.x, lane = t & 63, w = t >> 6;
  const int qt = (int)gridDim.x - 1 - (int)blockIdx.x;   // longest-first
  const int bh = blockIdx.y;
  const int b = bh >> 4, h = bh & 15;
  const int lr = lane & 15, lg = lane >> 4;
  const int q0w = qt*128 + w*32;

  __shared__ __attribute__((aligned(16))) unsigned short Kb[64*128];
  __shared__ __attribute__((aligned(16))) unsigned short Vb[128*64];
  __shared__ __attribute__((aligned(16))) unsigned short Ones[16*72];
  __shared__ __attribute__((aligned(16))) unsigned short P[4][32*72];
  unsigned short* pw = &P[w][0];

  for (int idx = t; idx < 16*72; idx += 256) Ones[idx] = (idx < 72) ? 0x3F80 : 0;

  short8 aq[2][4];
  {
    const unsigned short* qp = q + ((size_t)(b*SEQ + q0w + lr))*QKP + h*HDIM;
    #pragma unroll
    for (int mf=0;mf<2;mf++)
      #pragma unroll
      for (int c=0;c<4;c++) aq[mf][c] = *(const short8*)(qp + (size_t)mf*16*QKP + c*32 + lg*8);
  }

  f32x4 accO[2][8] = {};
  f32x4 accO9[2] = {};
  float mrow[2][4];
  #pragma unroll
  for (int mf=0;mf<2;mf++)
    #pragma unroll
    for (int r=0;r<4;r++) mrow[mf][r] = -3.0e38f;

  const float scale = 0.08838834764831845f;
  const unsigned short* kg = k + (size_t)(b*SEQ)*QKP + h*HDIM;
  const unsigned short* vg = vt + (size_t)(bh*HDIM)*SEQ;

  const unsigned short* kga[4]; const unsigned short* vga[4];
  unsigned short* kld[4]; unsigned short* vld[4];
  #pragma unroll
  for (int i=0;i<4;i++) {
    const int D = i*256 + t;
    const int rk = D >> 4, jk = D & 15;
    kga[i] = kg + (size_t)rk*QKP + ((jk ^ (rk & 7)) * 8);
    const int rv = D >> 3, jv = D & 7;
    vga[i] = vg + (size_t)rv*SEQ + ((jv ^ (rv & 7)) * 8);
    kld[i] = &Kb[i*2048 + w*512];
    vld[i] = &Vb[i*2048 + w*512];
  }

  const int KV_END = qt*128 + 128;

  for (int kv0 = 0; kv0 < KV_END; kv0 += 64) {
    #pragma unroll
    for (int i=0;i<4;i++) gload16(kga[i] + (size_t)kv0*QKP, kld[i]);
    #pragma unroll
    for (int i=0;i<4;i++) gload16(vga[i] + kv0, vld[i]);
    __syncthreads();

    if (kv0 < q0w + 32) {
      f32x4 sc[2][4] = {};
      #pragma unroll
      for (int blk=0;blk<4;blk++) {
        const int krow = blk*16 + lr;
        const int sw = (krow & 7) << 3;
        #pragma unroll
        for (int c=0;c<4;c++) {
          short8 bk = *(const short8*)&Kb[krow*128 + ((c*32 + lg*8) ^ sw)];
          sc[0][blk] = __builtin_amdgcn_mfma_f32_16x16x32_bf16(aq[0][c], bk, sc[0][blk], 0,0,0);
          sc[1][blk] = __builtin_amdgcn_mfma_f32_16x16x32_bf16(aq[1][c], bk, sc[1][blk], 0,0,0);
        }
      }
      #pragma unroll
      for (int mf=0;mf<2;mf++)
        #pragma unroll
        for (int blk=0;blk<4;blk++)
          #pragma unroll
          for (int r=0;r<4;r++) sc[mf][blk][r] *= scale;
      if (kv0 + 63 > q0w) {
        #pragma unroll
        for (int mf=0;mf<2;mf++)
          #pragma unroll
          for (int blk=0;blk<4;blk++)
            #pragma unroll
            for (int r=0;r<4;r++)
              if (kv0 + blk*16 + lr > q0w + mf*16 + lg*4 + r) sc[mf][blk][r] = -1.0e30f;
      }
      float pm[2][4];
      #pragma unroll
      for (int mf=0;mf<2;mf++)
        #pragma unroll
        for (int r=0;r<4;r++) {
          float m0 = fmaxf(fmaxf(sc[mf][0][r], sc[mf][1][r]), fmaxf(sc[mf][2][r], sc[mf][3][r]));
          #pragma unroll
          for (int x=1;x<16;x<<=1) m0 = fmaxf(m0, __shfl_xor(m0, x));
          pm[mf][r] = m0;
        }
      int need = 0;
      #pragma unroll
      for (int mf=0;mf<2;mf++)
        #pragma unroll
        for (int r=0;r<4;r++) need |= (pm[mf][r] > mrow[mf][r] + 8.0f) ? 1 : 0;
      if (__any(need)) {
        #pragma unroll
        for (int mf=0;mf<2;mf++)
          #pragma unroll
          for (int r=0;r<4;r++) {
            const float mn = fmaxf(mrow[mf][r], pm[mf][r]);
            const float fc = __expf(mrow[mf][r] - mn);
            mrow[mf][r] = mn;
            #pragma unroll
            for (int n=0;n<8;n++) accO[mf][n][r] *= fc;
            accO9[mf][r] *= fc;
          }
      }
      #pragma unroll
      for (int mf=0;mf<2;mf++)
        #pragma unroll
        for (int blk=0;blk<4;blk++)
          #pragma unroll
          for (int r=0;r<4;r++) {
            const float p = __expf(sc[mf][blk][r] - mrow[mf][r]);
            pw[(mf*16 + lg*4 + r)*72 + blk*16 + lr] = f2bf(p);
          }
      short8 ap[2][2];
      #pragma unroll
      for (int mf=0;mf<2;mf++)
        #pragma unroll
        for (int ks=0;ks<2;ks++) ap[mf][ks] = *(const short8*)&pw[(mf*16 + lr)*72 + ks*32 + lg*8];
      #pragma unroll
      for (int n=0;n<8;n++) {
        #pragma unroll
        for (int ks=0;ks<2;ks++) {
          const int vrow = n*16 + lr;
          const int sw = (vrow & 7) << 3;
          short8 bv = *(const short8*)&Vb[vrow*64 + ((ks*32 + lg*8) ^ sw)];
          accO[0][n] = __builtin_amdgcn_mfma_f32_16x16x32_bf16(ap[0][ks], bv, accO[0][n], 0,0,0);
          accO[1][n] = __builtin_amdgcn_mfma_f32_16x16x32_bf16(ap[1][ks], bv, accO[1][n], 0,0,0);
        }
      }
      #pragma unroll
      for (int ks=0;ks<2;ks++) {
        short8 bv9 = *(const short8*)&Ones[lr*72 + ks*32 + lg*8];
        accO9[0] = __builtin_amdgcn_mfma_f32_16x16x32_bf16(ap[0][ks], bv9, accO9[0], 0,0,0);
        accO9[1] = __builtin_amdgcn_mfma_f32_16x16x32_bf16(ap[1][ks], bv9, accO9[1], 0,0,0);
      }
    }
    __syncthreads();
  }

  #pragma unroll
  for (int mf=0;mf<2;mf++)
    #pragma unroll
    for (int r=0;r<4;r++) {
      const float lv = __shfl(accO9[mf][r], lane & 48);
      const float inv = 1.0f / lv;
      const size_t row = (size_t)(b*SEQ + q0w + mf*16 + lg*4 + r);
      #pragma unroll
      for (int n=0;n<8;n++)
        ao[row*DIM + h*HDIM + n*16 + lr] = f2bf(accO[mf][n][r] * inv);
    }
}

// ----------------------------------------------------------------------------
extern "C" void kernel_launch(void* const* d_in, const int* in_sizes, int n_in,
                              void* d_out, int out_size, void* d_ws, size_t ws_size,
                              hipStream_t stream) {
  (void)in_sizes; (void)n_in; (void)out_size; (void)ws_size;
  const float* x    = (const float*)d_in[0];
  const float* cosb = (const float*)d_in[1];
  const float* sinb = (const float*)d_in[2];
  // d_in[3] = mask (causal, analytic)
  const float* anw  = (const float*)d_in[4];
  const float* fnw  = (const float*)d_in[5];
  const float* wq   = (const float*)d_in[6];
  const float* wk   = (const float*)d_in[7];
  const float* wv   = (const float*)d_in[8];
  const float* wo   = (const float*)d_in[9];
  const float* w1   = (const float*)d_in[10];
  const float* w2   = (const float*)d_in[11];
  const float* w3   = (const float*)d_in[12];

  char* ws = (char*)d_ws;
  const size_t MB = 1048576;
  unsigned short* h     = (unsigned short*)(ws);            // 16 MB
  unsigned short* qkvb  = (unsigned short*)(ws + 16*MB);    // 50.3 MB
  unsigned short* mid   = qkvb;                             // 64 MB (FFN phase)
  unsigned short* aob   = (unsigned short*)(ws + 67*MB);    // 16 MB
  char* wt              = ws + 84*MB;                       // up to 64 MB scratch
  unsigned short* wqkvT = (unsigned short*)wt;              // 25.2 MB
  unsigned short* vtb   = (unsigned short*)wt;              // 16 MB (attn phase)
  unsigned short* woT   = (unsigned short*)wt;              // 8 MB
  unsigned short* w1T   = (unsigned short*)wt;              // 32 MB
  unsigned short* w3T   = (unsigned short*)(wt + 32*MB);    // 32 MB
  unsigned short* w2T   = (unsigned short*)wt;              // 32 MB (after FFN up)
  float* x1f = (float*)d_out;

  dim3 b256(256);
  constexpr unsigned LDS32 = 65536;    // gemm_pipe32: A 32KB + B 32KB
  constexpr unsigned LDS128 = 98304;   // gemm_pipe<128>: A 32KB + B 64KB

  rmsnorm_kernel<<<dim3(MROWS), b256, 0, stream>>>(x, anw, h);

  transpose3_kernel<<<dim3(32,32,3), b256, 0, stream>>>(wq, wk, wv,
      wqkvT, wqkvT + 4194304, wqkvT + 8388608, 2048, 2048);

  gemm_pipe32<0><<<dim3(384), dim3(512), LDS32, stream>>>(h, wqkvT, nullptr, qkvb, MROWS, 6144, 2048);

  rope_qk<<<dim3(32768), b256, 0, stream>>>(qkvb, cosb, sinb);

  transpose_v_kernel<<<dim3(64,64,2), b256, 0, stream>>>(qkvb + 4096, QKP, vtb);

  attn_kernel<<<dim3(16,32), b256, 0, stream>>>(qkvb, qkvb + 2048, vtb, aob);

  transpose3_kernel<<<dim3(32,32,1), b256, 0, stream>>>(wo, nullptr, nullptr,
      woT, nullptr, nullptr, 2048, 2048);
  gemm_pipe<128,1><<<dim3(256), dim3(512), LDS128, stream>>>(aob, woT, x, x1f, MROWS, 2048, 2048);

  rmsnorm_kernel<<<dim3(MROWS), b256, 0, stream>>>(x1f, fnw, h);

  // FFN: u = h@w1 -> mid (bf16); then g = h@w3 with fused silu(u)*g in-place.
  transpose3_kernel<<<dim3(32,128,2), b256, 0, stream>>>(w1, w3, nullptr,
      w1T, w3T, nullptr, 2048, 8192);
  gemm_pipe32<0><<<dim3(512), dim3(512), LDS32, stream>>>(h, w1T, nullptr, mid, MROWS, 8192, 2048);
  gemm_pipe32<3><<<dim3(512), dim3(512), LDS32, stream>>>(h, w3T, nullptr, mid, MROWS, 8192, 2048);

  transpose3_kernel<<<dim3(128,32,1), b256, 0, stream>>>(w2, nullptr, nullptr,
      w2T, nullptr, nullptr, 8192, 2048);
  gemm_pipe<128,1><<<dim3(256), dim3(512), LDS128, stream>>>(mid, w2T, x1f, (float*)d_out, MROWS, 2048, 8192);
}

// Round 17
// 810.295 us; speedup vs baseline: 1.0501x; 1.0501x over previous
//
#include <hip/hip_runtime.h>

#define DIM 2048
#define HDIM 128
#define NH 16
#define SEQ 2048
#define BATCH 2
#define MROWS (BATCH*SEQ)   // 4096
#define QKP 6144            // qkv row pitch (q|k|v concatenated)

typedef __attribute__((ext_vector_type(8))) short short8;
typedef __attribute__((ext_vector_type(4))) float f32x4;

template<int N> struct ic { static constexpr int value = N; };

__device__ __forceinline__ unsigned short f2bf(float f) {
  union { float f; unsigned u; } v; v.f = f;
  unsigned r = v.u + 0x7FFFu + ((v.u >> 16) & 1u);
  return (unsigned short)(r >> 16);
}
__device__ __forceinline__ float bf2f(unsigned short b) {
  union { unsigned u; float f; } v; v.u = ((unsigned)b) << 16;
  return v.f;
}

__device__ __forceinline__ void gload16(const void* g, void* l) {
  __builtin_amdgcn_global_load_lds((const __attribute__((address_space(1))) unsigned int*)g,
                                   (__attribute__((address_space(3))) unsigned int*)l,
                                   16, 0, 0);
}

// ---------------- RMSNorm: fp32 [rows][2048] -> bf16 ----------------
__global__ __launch_bounds__(256) void rmsnorm_kernel(const float* __restrict__ x,
                                                      const float* __restrict__ w,
                                                      unsigned short* __restrict__ out) {
  const int row = blockIdx.x;
  const int t = threadIdx.x;
  const float* xr = x + (size_t)row * DIM;
  float4 v0 = ((const float4*)xr)[t*2];
  float4 v1 = ((const float4*)xr)[t*2+1];
  float ss = v0.x*v0.x + v0.y*v0.y + v0.z*v0.z + v0.w*v0.w
           + v1.x*v1.x + v1.y*v1.y + v1.z*v1.z + v1.w*v1.w;
  #pragma unroll
  for (int i = 1; i < 64; i <<= 1) ss += __shfl_xor(ss, i);
  __shared__ float red[4];
  if ((t & 63) == 0) red[t >> 6] = ss;
  __syncthreads();
  float sum = red[0] + red[1] + red[2] + red[3];
  float sc = rsqrtf(sum * (1.0f/DIM) + 1e-6f);
  const float* wr = w + t*8;
  unsigned short ob[8];
  ob[0] = f2bf(v0.x*sc*wr[0]); ob[1] = f2bf(v0.y*sc*wr[1]);
  ob[2] = f2bf(v0.z*sc*wr[2]); ob[3] = f2bf(v0.w*sc*wr[3]);
  ob[4] = f2bf(v1.x*sc*wr[4]); ob[5] = f2bf(v1.y*sc*wr[5]);
  ob[6] = f2bf(v1.z*sc*wr[6]); ob[7] = f2bf(v1.w*sc*wr[7]);
  uint4 pk;
  pk.x = (unsigned)ob[0] | ((unsigned)ob[1] << 16);
  pk.y = (unsigned)ob[2] | ((unsigned)ob[3] << 16);
  pk.z = (unsigned)ob[4] | ((unsigned)ob[5] << 16);
  pk.w = (unsigned)ob[6] | ((unsigned)ob[7] << 16);
  *((uint4*)(out + (size_t)row*DIM + t*8)) = pk;
}

// ------- Wide transpose+cast: fp32 [K][N] -> bf16 [N][K], 64x64 tiles, z selects src -------
__global__ __launch_bounds__(256) void transpose3_kernel(const float* __restrict__ W0,
                                                         const float* __restrict__ W1,
                                                         const float* __restrict__ W2,
                                                         unsigned short* __restrict__ D0,
                                                         unsigned short* __restrict__ D1,
                                                         unsigned short* __restrict__ D2,
                                                         int K, int N) {
  const float* W = blockIdx.z == 0 ? W0 : (blockIdx.z == 1 ? W1 : W2);
  unsigned short* D = blockIdx.z == 0 ? D0 : (blockIdx.z == 1 ? D1 : D2);
  __shared__ float tile[64][65];
  const int k0 = blockIdx.x*64, n0 = blockIdx.y*64;
  const int t = threadIdx.x;
  const int rr = t >> 4, cc = (t & 15) * 4;
  #pragma unroll
  for (int i=0;i<4;i++) {
    float4 v = *(const float4*)&W[(size_t)(k0 + rr + i*16)*N + n0 + cc];
    tile[rr+i*16][cc] = v.x; tile[rr+i*16][cc+1] = v.y;
    tile[rr+i*16][cc+2] = v.z; tile[rr+i*16][cc+3] = v.w;
  }
  __syncthreads();
  #pragma unroll
  for (int j=0;j<4;j++) {
    const int n = rr + j*16;
    uint2 pk;
    pk.x = (unsigned)f2bf(tile[cc  ][n]) | ((unsigned)f2bf(tile[cc+1][n]) << 16);
    pk.y = (unsigned)f2bf(tile[cc+2][n]) | ((unsigned)f2bf(tile[cc+3][n]) << 16);
    *(uint2*)&D[(size_t)(n0 + n)*K + k0 + cc] = pk;
  }
}

// ------------- V transpose (bf16): [b*S][vpitch cols 0..2047] -> [b*2048][S] -------------
__global__ __launch_bounds__(256) void transpose_v_kernel(const unsigned short* __restrict__ v,
                                                          int vpitch,
                                                          unsigned short* __restrict__ vt) {
  __shared__ unsigned short tile[32][33];
  const int b = blockIdx.z;
  const int s0 = blockIdx.x*32, c0 = blockIdx.y*32;
  const int tx = threadIdx.x & 31, ty = threadIdx.x >> 5;
  #pragma unroll
  for (int i=0;i<4;i++) tile[ty+i*8][tx] = v[((size_t)(b*SEQ + s0+ty+i*8))*vpitch + c0+tx];
  __syncthreads();
  #pragma unroll
  for (int i=0;i<4;i++) vt[((size_t)(b*DIM + c0+ty+i*8))*SEQ + s0+tx] = tile[tx][ty+i*8];
}

// ------------- RoPE in-place on q|k halves of qkv buffer [4096][QKP] -------------
__global__ __launch_bounds__(256) void rope_qk(unsigned short* __restrict__ qk,
                                               const float* __restrict__ cosb,
                                               const float* __restrict__ sinb) {
  const size_t idx = (size_t)blockIdx.x * 256 + threadIdx.x; // pair index
  const int d = (int)(idx & 63);
  const int h = (int)((idx >> 6) & 31);   // 32 head-slots: q heads 0-15, k heads 16-31
  const int row = (int)(idx >> 11);       // 0..4095
  const int s = row & (SEQ-1);
  const size_t base = (size_t)row * QKP + h*HDIM + d;
  float a  = bf2f(qk[base]);
  float bq = bf2f(qk[base+64]);
  float c1 = cosb[s*HDIM + d],    s1 = sinb[s*HDIM + d];
  float c2 = cosb[s*HDIM + d+64], s2 = sinb[s*HDIM + d+64];
  qk[base]    = f2bf(a*c1 - bq*s1);
  qk[base+64] = f2bf(bq*c2 + a*s2);
}

// ------------- 8-phase pipelined GEMM (r10, best-measured): C = A @ Bt^T -------------
template<int BM, int EPI>
__global__ __launch_bounds__(512, 2) void gemm_pipe(const unsigned short* __restrict__ A,
                                                    const unsigned short* __restrict__ Bt,
                                                    const float* __restrict__ aux,
                                                    void* __restrict__ outp,
                                                    int M, int N, int K) {
  constexpr int HRA = BM/2;
  constexpr int MF  = BM/32;
  constexpr int APP = MF/4;
  constexpr int LA  = BM/128;
  constexpr int AHS = HRA*64;
  constexpr int BB  = 4*AHS;
  extern __shared__ unsigned short ldsd[];
  const int tid = threadIdx.x, l = tid & 63, wid = tid >> 6;
  const int wm = wid >> 2, wn = wid & 3;
  const int lr = l & 15, lg = l >> 4;
  const int bh = wn >> 1, brow0 = (wn & 1)*64;

  const int nbx = N >> 8;
  const int SW = (nbx >= 8) ? (nbx >> 3) : 1;
  const int xcd = (int)blockIdx.x & 7;
  const int ii  = (int)blockIdx.x >> 3;
  const int by = ii / SW;
  const int bx = xcd * SW + (ii % SW);
  const int m0 = by * BM, n0 = bx * 256;

  const int m7 = lr & 7;
  const int jks0 = ((lg    ) ^ m7) << 3;
  const int jks1 = ((4 + lg) ^ m7) << 3;
  const unsigned short* ldsA0 = ldsd + wm*AHS + lr*64;
  const unsigned short* ldsA1 = ldsA0 + 2*AHS;
  const unsigned short* ldsB0 = ldsd + BB + bh*8192 + (brow0+lr)*64;
  const unsigned short* ldsB1 = ldsB0 + 2*8192;

  const int r0 = tid >> 3;
  const int jsw = ((tid & 7) ^ (r0 & 7)) << 3;
  const unsigned short* srcA[2][LA];
  #pragma unroll
  for (int h=0;h<2;h++)
    #pragma unroll
    for (int c=0;c<LA;c++)
      srcA[h][c] = A + (size_t)(m0 + h*HRA + c*64 + r0)*K + jsw;
  const unsigned short* srcB[2][2];
  #pragma unroll
  for (int h=0;h<2;h++)
    #pragma unroll
    for (int c=0;c<2;c++)
      srcB[h][c] = Bt + (size_t)(n0 + h*128 + c*64 + r0)*K + jsw;
  unsigned short* dstL = ldsd + tid*8;

  int kO = 0;
  auto stA = [&](int db, int half, int tiled) {
    #pragma unroll
    for (int c=0;c<LA;c++)
      gload16(srcA[half][c] + kO + tiled, dstL + (db*2+half)*AHS + c*4096);
  };
  auto stB = [&](int db, int half, int tiled) {
    #pragma unroll
    for (int c=0;c<2;c++)
      gload16(srcB[half][c] + kO + tiled, dstL + BB + (db*2+half)*8192 + c*4096);
  };

  f32x4 acc[MF][4] = {};
  short8 bfrag[4][2];
  const int ntile = K >> 6;

  stB(0,0,0); stB(0,1,0);
  stA(0,0,0); stA(0,1,0);
  stB(1,0,64); stB(1,1,64);
  asm volatile("s_waitcnt vmcnt(4)" ::: "memory");
  __builtin_amdgcn_sched_barrier(0);
  __builtin_amdgcn_s_barrier();

  auto phase = [&](auto PC, auto LC) {
    constexpr int P = decltype(PC)::value;
    constexpr int LAST = decltype(LC)::value;
    constexpr int hi = P >> 2;
    constexpr int p  = P & 3;
    if constexpr (p == 0) {
      const unsigned short* bB = hi ? ldsB1 : ldsB0;
      #pragma unroll
      for (int nf=0;nf<4;nf++) {
        bfrag[nf][0] = *(const short8*)(bB + nf*1024 + jks0);
        bfrag[nf][1] = *(const short8*)(bB + nf*1024 + jks1);
      }
    }
    const unsigned short* aB = hi ? ldsA1 : ldsA0;
    short8 afr[APP][2];
    #pragma unroll
    for (int mi=0;mi<APP;mi++) {
      afr[mi][0] = *(const short8*)(aB + (p*APP+mi)*1024 + jks0);
      afr[mi][1] = *(const short8*)(aB + (p*APP+mi)*1024 + jks1);
    }
    if constexpr (P == 0)      stA(1, 0, 64);
    else if constexpr (P == 1) stA(1, 1, 64);
    else if constexpr (!LAST) {
      if constexpr (P == 2)      stB(0, 0, 128);
      else if constexpr (P == 3) stB(0, 1, 128);
      else if constexpr (P == 4) stA(0, 0, 128);
      else if constexpr (P == 5) stA(0, 1, 128);
      else if constexpr (P == 6) stB(1, 0, 192);
      else if constexpr (P == 7) stB(1, 1, 192);
    }
    if constexpr (p == 0) {
      asm volatile("s_waitcnt lgkmcnt(8)" ::: "memory");
    }
    if constexpr (P == 3) {
      if constexpr (LAST) { asm volatile("s_waitcnt vmcnt(0)" ::: "memory"); }
      else                { asm volatile("s_waitcnt vmcnt(4)" ::: "memory"); }
    }
    if constexpr (P == 7 && !LAST) {
      asm volatile("s_waitcnt vmcnt(4)" ::: "memory");
    }
    __builtin_amdgcn_s_barrier();
    asm volatile("s_waitcnt lgkmcnt(0)" ::: "memory");
    __builtin_amdgcn_sched_barrier(0);
    __builtin_amdgcn_s_setprio(1);
    #pragma unroll
    for (int mi=0;mi<APP;mi++)
      #pragma unroll
      for (int nf=0;nf<4;nf++)
        #pragma unroll
        for (int ks=0;ks<2;ks++)
          acc[p*APP+mi][nf] = __builtin_amdgcn_mfma_f32_16x16x32_bf16(afr[mi][ks], bfrag[nf][ks], acc[p*APP+mi][nf], 0,0,0);
    __builtin_amdgcn_s_setprio(0);
    __builtin_amdgcn_s_barrier();
  };

  for (int T = 0; T + 2 < ntile; T += 2, kO += 128) {
    phase(ic<0>{}, ic<0>{}); phase(ic<1>{}, ic<0>{});
    phase(ic<2>{}, ic<0>{}); phase(ic<3>{}, ic<0>{});
    phase(ic<4>{}, ic<0>{}); phase(ic<5>{}, ic<0>{});
    phase(ic<6>{}, ic<0>{}); phase(ic<7>{}, ic<0>{});
  }
  phase(ic<0>{}, ic<1>{}); phase(ic<1>{}, ic<1>{});
  phase(ic<2>{}, ic<1>{}); phase(ic<3>{}, ic<1>{});
  phase(ic<4>{}, ic<1>{}); phase(ic<5>{}, ic<1>{});
  phase(ic<6>{}, ic<1>{}); phase(ic<7>{}, ic<1>{});

  #pragma unroll
  for (int mf = 0; mf < MF; mf++)
    #pragma unroll
    for (int nf = 0; nf < 4; nf++)
      #pragma unroll
      for (int r = 0; r < 4; r++) {
        const int row = m0 + wm*HRA + mf*16 + lg*4 + r;
        const int col = n0 + wn*64 + nf*16 + lr;
        const size_t idx = (size_t)row * N + col;
        if constexpr (EPI == 0) {
          ((unsigned short*)outp)[idx] = f2bf(acc[mf][nf][r]);
        } else if constexpr (EPI == 1) {
          ((float*)outp)[idx] = acc[mf][nf][r] + aux[idx];
        } else {
          float g = acc[mf][nf][r];
          float u = bf2f(((unsigned short*)outp)[idx]);
          float sg = u / (1.0f + __expf(-u));
          ((unsigned short*)outp)[idx] = f2bf(sg * g);
        }
      }
}

// ------------- Flash attention (causal), 128-row q-tiles, KVBLK=64 -------------
__global__ __launch_bounds__(256, 2) void attn_kernel(const unsigned short* __restrict__ q,
                                                      const unsigned short* __restrict__ k,
                                                      const unsigned short* __restrict__ vt,
                                                      unsigned short* __restrict__ ao) {
  const int t = threadIdx.x, lane = t & 63, w = t >> 6;
  const int qt = (int)gridDim.x - 1 - (int)blockIdx.x;   // longest-first
  const int bh = blockIdx.y;
  const int b = bh >> 4, h = bh & 15;
  const int lr = lane & 15, lg = lane >> 4;
  const int q0w = qt*128 + w*32;

  __shared__ __attribute__((aligned(16))) unsigned short Kb[64*128];
  __shared__ __attribute__((aligned(16))) unsigned short Vb[128*64];
  __shared__ __attribute__((aligned(16))) unsigned short Ones[16*72];
  __shared__ __attribute__((aligned(16))) unsigned short P[4][32*72];
  unsigned short* pw = &P[w][0];

  for (int idx = t; idx < 16*72; idx += 256) Ones[idx] = (idx < 72) ? 0x3F80 : 0;

  short8 aq[2][4];
  {
    const unsigned short* qp = q + ((size_t)(b*SEQ + q0w + lr))*QKP + h*HDIM;
    #pragma unroll
    for (int mf=0;mf<2;mf++)
      #pragma unroll
      for (int c=0;c<4;c++) aq[mf][c] = *(const short8*)(qp + (size_t)mf*16*QKP + c*32 + lg*8);
  }

  f32x4 accO[2][8] = {};
  f32x4 accO9[2] = {};
  float mrow[2][4];
  #pragma unroll
  for (int mf=0;mf<2;mf++)
    #pragma unroll
    for (int r=0;r<4;r++) mrow[mf][r] = -3.0e38f;

  const float scale = 0.08838834764831845f;
  const unsigned short* kg = k + (size_t)(b*SEQ)*QKP + h*HDIM;
  const unsigned short* vg = vt + (size_t)(bh*HDIM)*SEQ;

  const unsigned short* kga[4]; const unsigned short* vga[4];
  unsigned short* kld[4]; unsigned short* vld[4];
  #pragma unroll
  for (int i=0;i<4;i++) {
    const int D = i*256 + t;
    const int rk = D >> 4, jk = D & 15;
    kga[i] = kg + (size_t)rk*QKP + ((jk ^ (rk & 7)) * 8);
    const int rv = D >> 3, jv = D & 7;
    vga[i] = vg + (size_t)rv*SEQ + ((jv ^ (rv & 7)) * 8);
    kld[i] = &Kb[i*2048 + w*512];
    vld[i] = &Vb[i*2048 + w*512];
  }

  const int KV_END = qt*128 + 128;

  for (int kv0 = 0; kv0 < KV_END; kv0 += 64) {
    #pragma unroll
    for (int i=0;i<4;i++) gload16(kga[i] + (size_t)kv0*QKP, kld[i]);
    #pragma unroll
    for (int i=0;i<4;i++) gload16(vga[i] + kv0, vld[i]);
    __syncthreads();

    if (kv0 < q0w + 32) {
      f32x4 sc[2][4] = {};
      #pragma unroll
      for (int blk=0;blk<4;blk++) {
        const int krow = blk*16 + lr;
        const int sw = (krow & 7) << 3;
        #pragma unroll
        for (int c=0;c<4;c++) {
          short8 bk = *(const short8*)&Kb[krow*128 + ((c*32 + lg*8) ^ sw)];
          sc[0][blk] = __builtin_amdgcn_mfma_f32_16x16x32_bf16(aq[0][c], bk, sc[0][blk], 0,0,0);
          sc[1][blk] = __builtin_amdgcn_mfma_f32_16x16x32_bf16(aq[1][c], bk, sc[1][blk], 0,0,0);
        }
      }
      #pragma unroll
      for (int mf=0;mf<2;mf++)
        #pragma unroll
        for (int blk=0;blk<4;blk++)
          #pragma unroll
          for (int r=0;r<4;r++) sc[mf][blk][r] *= scale;
      if (kv0 + 63 > q0w) {
        #pragma unroll
        for (int mf=0;mf<2;mf++)
          #pragma unroll
          for (int blk=0;blk<4;blk++)
            #pragma unroll
            for (int r=0;r<4;r++)
              if (kv0 + blk*16 + lr > q0w + mf*16 + lg*4 + r) sc[mf][blk][r] = -1.0e30f;
      }
      float pm[2][4];
      #pragma unroll
      for (int mf=0;mf<2;mf++)
        #pragma unroll
        for (int r=0;r<4;r++) {
          float m0 = fmaxf(fmaxf(sc[mf][0][r], sc[mf][1][r]), fmaxf(sc[mf][2][r], sc[mf][3][r]));
          #pragma unroll
          for (int x=1;x<16;x<<=1) m0 = fmaxf(m0, __shfl_xor(m0, x));
          pm[mf][r] = m0;
        }
      int need = 0;
      #pragma unroll
      for (int mf=0;mf<2;mf++)
        #pragma unroll
        for (int r=0;r<4;r++) need |= (pm[mf][r] > mrow[mf][r] + 8.0f) ? 1 : 0;
      if (__any(need)) {
        #pragma unroll
        for (int mf=0;mf<2;mf++)
          #pragma unroll
          for (int r=0;r<4;r++) {
            const float mn = fmaxf(mrow[mf][r], pm[mf][r]);
            const float fc = __expf(mrow[mf][r] - mn);
            mrow[mf][r] = mn;
            #pragma unroll
            for (int n=0;n<8;n++) accO[mf][n][r] *= fc;
            accO9[mf][r] *= fc;
          }
      }
      #pragma unroll
      for (int mf=0;mf<2;mf++)
        #pragma unroll
        for (int blk=0;blk<4;blk++)
          #pragma unroll
          for (int r=0;r<4;r++) {
            const float p = __expf(sc[mf][blk][r] - mrow[mf][r]);
            pw[(mf*16 + lg*4 + r)*72 + blk*16 + lr] = f2bf(p);
          }
      short8 ap[2][2];
      #pragma unroll
      for (int mf=0;mf<2;mf++)
        #pragma unroll
        for (int ks=0;ks<2;ks++) ap[mf][ks] = *(const short8*)&pw[(mf*16 + lr)*72 + ks*32 + lg*8];
      #pragma unroll
      for (int n=0;n<8;n++) {
        #pragma unroll
        for (int ks=0;ks<2;ks++) {
          const int vrow = n*16 + lr;
          const int sw = (vrow & 7) << 3;
          short8 bv = *(const short8*)&Vb[vrow*64 + ((ks*32 + lg*8) ^ sw)];
          accO[0][n] = __builtin_amdgcn_mfma_f32_16x16x32_bf16(ap[0][ks], bv, accO[0][n], 0,0,0);
          accO[1][n] = __builtin_amdgcn_mfma_f32_16x16x32_bf16(ap[1][ks], bv, accO[1][n], 0,0,0);
        }
      }
      #pragma unroll
      for (int ks=0;ks<2;ks++) {
        short8 bv9 = *(const short8*)&Ones[lr*72 + ks*32 + lg*8];
        accO9[0] = __builtin_amdgcn_mfma_f32_16x16x32_bf16(ap[0][ks], bv9, accO9[0], 0,0,0);
        accO9[1] = __builtin_amdgcn_mfma_f32_16x16x32_bf16(ap[1][ks], bv9, accO9[1], 0,0,0);
      }
    }
    __syncthreads();
  }

  #pragma unroll
  for (int mf=0;mf<2;mf++)
    #pragma unroll
    for (int r=0;r<4;r++) {
      const float lv = __shfl(accO9[mf][r], lane & 48);
      const float inv = 1.0f / lv;
      const size_t row = (size_t)(b*SEQ + q0w + mf*16 + lg*4 + r);
      #pragma unroll
      for (int n=0;n<8;n++)
        ao[row*DIM + h*HDIM + n*16 + lr] = f2bf(accO[mf][n][r] * inv);
    }
}

// ----------------------------------------------------------------------------
extern "C" void kernel_launch(void* const* d_in, const int* in_sizes, int n_in,
                              void* d_out, int out_size, void* d_ws, size_t ws_size,
                              hipStream_t stream) {
  (void)in_sizes; (void)n_in; (void)out_size; (void)ws_size;
  const float* x    = (const float*)d_in[0];
  const float* cosb = (const float*)d_in[1];
  const float* sinb = (const float*)d_in[2];
  // d_in[3] = mask (causal, analytic)
  const float* anw  = (const float*)d_in[4];
  const float* fnw  = (const float*)d_in[5];
  const float* wq   = (const float*)d_in[6];
  const float* wk   = (const float*)d_in[7];
  const float* wv   = (const float*)d_in[8];
  const float* wo   = (const float*)d_in[9];
  const float* w1   = (const float*)d_in[10];
  const float* w2   = (const float*)d_in[11];
  const float* w3   = (const float*)d_in[12];

  char* ws = (char*)d_ws;
  const size_t MB = 1048576;
  unsigned short* h     = (unsigned short*)(ws);            // 16 MB
  unsigned short* qkvb  = (unsigned short*)(ws + 16*MB);    // 50.3 MB
  unsigned short* mid   = qkvb;                             // 64 MB (FFN phase)
  unsigned short* aob   = (unsigned short*)(ws + 67*MB);    // 16 MB
  char* wt              = ws + 84*MB;                       // up to 64 MB scratch
  unsigned short* wqkvT = (unsigned short*)wt;              // 25.2 MB
  unsigned short* vtb   = (unsigned short*)wt;              // 16 MB (attn phase)
  unsigned short* woT   = (unsigned short*)wt;              // 8 MB
  unsigned short* w1T   = (unsigned short*)wt;              // 32 MB
  unsigned short* w3T   = (unsigned short*)(wt + 32*MB);    // 32 MB
  unsigned short* w2T   = (unsigned short*)wt;              // 32 MB (after FFN up)
  float* x1f = (float*)d_out;

  dim3 b256(256);
  constexpr unsigned LDS256 = 131072;  // A 64KB + B 64KB
  constexpr unsigned LDS128 = 98304;   // A 32KB + B 64KB

  rmsnorm_kernel<<<dim3(MROWS), b256, 0, stream>>>(x, anw, h);

  transpose3_kernel<<<dim3(32,32,3), b256, 0, stream>>>(wq, wk, wv,
      wqkvT, wqkvT + 4194304, wqkvT + 8388608, 2048, 2048);

  // QKV: BM=128 -> 32 x 24 = 768 blocks = exactly 3 full occupancy rounds
  gemm_pipe<128,0><<<dim3(768), dim3(512), LDS128, stream>>>(h, wqkvT, nullptr, qkvb, MROWS, 6144, 2048);

  rope_qk<<<dim3(32768), b256, 0, stream>>>(qkvb, cosb, sinb);

  transpose_v_kernel<<<dim3(64,64,2), b256, 0, stream>>>(qkvb + 4096, QKP, vtb);

  attn_kernel<<<dim3(16,32), b256, 0, stream>>>(qkvb, qkvb + 2048, vtb, aob);

  transpose3_kernel<<<dim3(32,32,1), b256, 0, stream>>>(wo, nullptr, nullptr,
      woT, nullptr, nullptr, 2048, 2048);
  gemm_pipe<128,1><<<dim3(256), dim3(512), LDS128, stream>>>(aob, woT, x, x1f, MROWS, 2048, 2048);

  rmsnorm_kernel<<<dim3(MROWS), b256, 0, stream>>>(x1f, fnw, h);

  // FFN: u = h@w1 -> mid (bf16); then g = h@w3 with fused silu(u)*g in-place.
  transpose3_kernel<<<dim3(32,128,2), b256, 0, stream>>>(w1, w3, nullptr,
      w1T, w3T, nullptr, 2048, 8192);
  gemm_pipe<256,0><<<dim3(512), dim3(512), LDS256, stream>>>(h, w1T, nullptr, mid, MROWS, 8192, 2048);
  gemm_pipe<256,3><<<dim3(512), dim3(512), LDS256, stream>>>(h, w3T, nullptr, mid, MROWS, 8192, 2048);

  transpose3_kernel<<<dim3(128,32,1), b256, 0, stream>>>(w2, nullptr, nullptr,
      w2T, nullptr, nullptr, 8192, 2048);
  gemm_pipe<128,1><<<dim3(256), dim3(512), LDS128, stream>>>(mid, w2T, x1f, (float*)d_out, MROWS, 2048, 8192);
}